// Round 10
// baseline (16881.013 us; speedup 1.0000x reference)
//
#include <hip/hip_runtime.h>

// ============================================================================
// Fully block-local attention-LSTM encoder. B=512, T-1=99, N=128, H=256.
//
// R15 == R14 resubmitted verbatim (R14 bench died "container failed twice",
// same signature as R6 which passed on identical resubmit R7; audit found no
// deadlock/OOB/LDS-overflow -> infra flake).
//
// R14: register-parking is dead (R11-R13: hipcc caps VGPRs at 65536/threads
// regardless of launch_bounds arg2; parked arrays spill -> 21-24GB scratch).
// Flip the constraint: 1024-thread blocks (cap 64 VGPR) as a LEAN STREAMING
// kernel with 16 waves (4/SIMD, 2x R9's TLP for latency hiding):
//  - each thread owns exactly ONE gate row j=tid (1024 rows): per-step
//    per-thread work halves vs R9 (384 gate dot2 + 64 z1 + ~150 E VALU)
//  - weights streamed as coalesced u4 (16B/lane) in software-pipelined
//    4-load groups; live set ~55 regs < 64 cap (no parked arrays)
//  - 3 h-kbs (48KB) parked in LDS scratch (dead after z2 prologue)
//  - gates-h stream + E-phase share one barrier region (m114 co-schedule);
//    gates-w loads issued BEFORE softmax so latency hides under it
//  - E-phase 4-way s-split (25/25/25/24) across 1024 threads
// Phases: P1 z1+parked-h -> P2 reduce -> P3 h-stream+E -> P4 softmax
//         -> P5 w-stream -> P6 LSTM. 6 barriers/step. No flags, no sc1.
// Numerics: f16 pairs + fdot2 + f32 accum (R9-proven, absmax 4.88e-4).
// 256 blocks x 1024 threads, 1 block/CU (LDS ~130KB).
// ============================================================================

typedef unsigned int  uint32;
typedef unsigned short u16;
typedef _Float16 h2  __attribute__((ext_vector_type(2)));
typedef uint32   u4  __attribute__((ext_vector_type(4)));

#define TS 99
#define BB 512
#define NN 128
#define HH 256

__device__ __forceinline__ float frcp(float x){ return __builtin_amdgcn_rcpf(x); }
__device__ __forceinline__ float ftanh(float x){
  float t = __expf(2.f * x);
  return 1.f - 2.f * frcp(t + 1.f);
}
__device__ __forceinline__ float fsig(float x){
  return frcp(1.f + __expf(-x));
}
__device__ __forceinline__ uint32 pk2(float a, float b){
  union { h2 h; uint32 u; } v;
  v.h[0] = (_Float16)a; v.h[1] = (_Float16)b; return v.u;
}
__device__ __forceinline__ u16 f2h(float f){
  union { _Float16 h; u16 u; } v; v.h = (_Float16)f; return v.u;
}
__device__ __forceinline__ float h2ff(u16 u){
  union { u16 u2; _Float16 h; } v; v.u2 = u; return (float)v.h;
}
__device__ __forceinline__ float dot2(uint32 a, uint32 b, float c){
  union { uint32 u; h2 h; } x, y; x.u = a; y.u = b;
#if __has_builtin(__builtin_amdgcn_fdot2)
  return __builtin_amdgcn_fdot2(x.h, y.h, c, false);
#else
  c = fmaf((float)x.h[0], (float)y.h[0], c);
  return fmaf((float)x.h[1], (float)y.h[1], c);
#endif
}

struct KParams {
  const float *in, *W1, *b1, *W2, *b2, *W3, *Wih, *Whh, *bih, *bhh;
  float *out;        // [weighted B*99*128 | encoded B*99*256] f32
  const u4 *Wh4;     // [32 kb][1024 j] u4: Whh row j, h-pairs kb*4..+3
  const u4 *Ww4;     // [16 kb][1024 j] u4: Wih row j, w-pairs kb*4..+3
  const u4 *W1c;     // [64 kpb][128 s] u4: W1[s], k-pairs kpb*4..+3 ([h|c])
};

// ---- pack weights to f16-pair u4 layouts (runs once; ~0.9MB) ----
__global__ void pack_kernel(const float* W1, const float* Wih, const float* Whh,
                            uint32* Wh4, uint32* Ww4, uint32* W1c)
{
  int idx = blockIdx.x * 256 + threadIdx.x;
  if (idx < 32 * 1024 * 4) {                    // Wh4[kb][j][i]
    int i = idx & 3, j = (idx >> 2) & 1023, kb = idx >> 12;
    int ph = kb * 4 + i;                        // h-pair 0..127
    Wh4[idx] = pk2(Whh[(size_t)j * 256 + 2 * ph],
                   Whh[(size_t)j * 256 + 2 * ph + 1]);
  } else if (idx < 32 * 1024 * 4 + 16 * 1024 * 4) {
    int v = idx - 32 * 1024 * 4;                // Ww4[kb][j][i]
    int i = v & 3, j = (v >> 2) & 1023, kb = v >> 12;
    int pw = kb * 4 + i;                        // w-pair 0..63
    Ww4[v] = pk2(Wih[(size_t)j * 128 + 2 * pw],
                 Wih[(size_t)j * 128 + 2 * pw + 1]);
  } else {
    int w = idx - (32 * 1024 * 4 + 16 * 1024 * 4);
    if (w < 64 * 128 * 4) {                     // W1c[kpb][s][i]
      int i = w & 3, s = (w >> 2) & 127, kpb = w >> 9;
      int kp = kpb * 4 + i;                     // k-pair over [h(128)|c(128)]
      uint32 r = 0;
      if (s < TS) r = pk2(W1[(size_t)s * 512 + 2 * kp],
                          W1[(size_t)s * 512 + 2 * kp + 1]);
      W1c[w] = r;
    }
  }
}

// consume one u4 of gate weights against batch broadcasts x0/x1
#define HC1(W, kb) do { u4 x0_ = hc0[kb], x1_ = hc1[kb];               \
    _Pragma("unroll")                                                  \
    for (int ii_ = 0; ii_ < 4; ++ii_) {                                \
      ga0 = dot2(W[ii_], x0_[ii_], ga0);                               \
      ga1 = dot2(W[ii_], x1_[ii_], ga1);                               \
    } } while (0)
#define WC1(W, kb) do { u4 x0_ = wp0[kb], x1_ = wp1[kb];               \
    _Pragma("unroll")                                                  \
    for (int ii_ = 0; ii_ < 4; ++ii_) {                                \
      ga0 = dot2(W[ii_], x0_[ii_], ga0);                               \
      ga1 = dot2(W[ii_], x1_[ii_], ga1);                               \
    } } while (0)

__global__ __launch_bounds__(1024, 1) void enc_kernel(KParams p)
{
  // scratch: in[b][n][t] during prologue, then h-kb park (3 kbs = 48KB)
  __shared__ __align__(16) u16    scratch[2][128][102];  // 52,224 B
  __shared__ __align__(16) u16    z2s[2][128][102];      // f16 z2[b][n][s]
  __shared__ __align__(16) uint32 hcp[2][256];           // f16 pairs: h|c
  __shared__ __align__(16) uint32 wp[2][64];             // f16 pairs: w[n]
  __shared__ __align__(16) float  z1part[2][8][128];
  __shared__ __align__(16) float  z1s[2][128];
  __shared__ float epart[2][4][128];
  __shared__ float gl[2][1024];
  __shared__ float w3s[128], b1s[128];

  const int tid = threadIdx.x;
  const int blk = blockIdx.x;
  const int b0  = blk * 2;               // this block's two batches

  float* outw = p.out;
  float* oute = p.out + (size_t)BB * TS * NN;

  // ---------------- prologue ----------------
  for (int b = 0; b < 2; ++b) {          // stage inputs f16, column layout
    const float* src = p.in + (size_t)(b0 + b) * TS * NN;
    for (int idx = tid; idx < TS * NN; idx += 1024) {
      int tt = idx >> 7, n = idx & 127;
      scratch[b][n][tt] = f2h(src[idx]);
    }
  }
  if (tid < 128) {
    w3s[tid] = (tid < TS) ? p.W3[tid] : 0.f;
    b1s[tid] = (tid < TS) ? p.b1[tid] : 0.f;
  }
  if (tid < 512) hcp[tid >> 8][tid & 255] = 0;   // h = c = 0 at t=0
  const float br = p.bih[tid] + p.bhh[tid];      // bias of own gate row
  __syncthreads();
  {  // z2[b][n][s] = b2[s] + sum_t in[b][t][n] * W2[s][t]  (4-way s-split)
    int n = tid & 127, b = (tid >> 7) & 1, hf = tid >> 8;
    int s0 = hf * 25, s1 = s0 + ((hf == 3) ? 24 : 25);
    const u16* ir = scratch[b][n];
    for (int s = s0; s < s1; ++s) {
      float acc = p.b2[s];
      const float* w2r = p.W2 + s * TS;
      for (int tt = 0; tt + 1 < TS; tt += 2) {
        uint32 pr = *(const uint32*)&ir[tt];
        acc = fmaf(h2ff((u16)(pr & 0xFFFFu)), w2r[tt],     acc);
        acc = fmaf(h2ff((u16)(pr >> 16)),     w2r[tt + 1], acc);
      }
      acc = fmaf(h2ff(ir[98]), w2r[98], acc);
      z2s[b][n][s] = f2h(acc);
    }
  }
  __syncthreads();
  // ---- LDS-park h kbs 0..2 into dead scratch (48KB) ----
  u4* hp4 = (u4*)&scratch[0][0][0];
  #pragma unroll
  for (int r = 0; r < 3; ++r) hp4[r * 1024 + tid] = p.Wh4[r * 1024 + tid];
  __syncthreads();

  float creg = 0.f;                      // c for (lb, lu), f32 forever
  const int lu = tid & 255, lb = (tid >> 8) & 1;   // LSTM role (tid<512)

  const u4* wh4g = p.Wh4;
  const u4* ww4g = p.Ww4;
  const u4* w1c4 = p.W1c;
  const u4* hc0  = (const u4*)&hcp[0][0];   // u4 0..31 = h, 32..63 = c
  const u4* hc1  = (const u4*)&hcp[1][0];
  const u4* wp0  = (const u4*)&wp[0][0];
  const u4* wp1  = (const u4*)&wp[1][0];

  for (int t = 0; t < TS; ++t) {
    // block LICM of loop-invariant weight loads (R11-R13 hoist/spill trap)
    asm volatile("" : "+s"(wh4g), "+s"(ww4g), "+s"(w1c4));

    float x0v = 0.f, x1v = 0.f;          // x_t prefetch for softmax
    if (tid < 128) {
      int b = tid >> 6, ln = tid & 63;
      const float* xr = p.in + ((size_t)(b0 + b) * TS + t) * NN;
      x0v = xr[ln]; x1v = xr[ln + 64];
    }

    float ga0 = 0.f, ga1 = 0.f;          // gate row tid, batches 0/1

    // ===== P1: z1 stream+consume, parked-h consume under load latency =====
    {
      int s = tid & 127, q = tid >> 7;   // s-slot, k-eighth (32 pairs)
      u4 wv0 = w1c4[(q * 8 + 0) * 128 + s];
      u4 wv1 = w1c4[(q * 8 + 1) * 128 + s];
      u4 wv2 = w1c4[(q * 8 + 2) * 128 + s];
      u4 wv3 = w1c4[(q * 8 + 3) * 128 + s];
      u4 wv4 = w1c4[(q * 8 + 4) * 128 + s];
      u4 wv5 = w1c4[(q * 8 + 5) * 128 + s];
      u4 wv6 = w1c4[(q * 8 + 6) * 128 + s];
      u4 wv7 = w1c4[(q * 8 + 7) * 128 + s];
      #pragma unroll
      for (int kb = 0; kb < 3; ++kb) {   // parked h-kbs (LDS)
        u4 w = hp4[kb * 1024 + tid];
        HC1(w, kb);
      }
      float za0 = 0.f, za1 = 0.f;
      #define ZC1(W, i) do { u4 x0_ = hc0[q * 8 + (i)], x1_ = hc1[q * 8 + (i)]; \
          _Pragma("unroll")                                                     \
          for (int ii_ = 0; ii_ < 4; ++ii_) {                                   \
            za0 = dot2(W[ii_], x0_[ii_], za0);                                  \
            za1 = dot2(W[ii_], x1_[ii_], za1);                                  \
          } } while (0)
      ZC1(wv0, 0); ZC1(wv1, 1); ZC1(wv2, 2); ZC1(wv3, 3);
      ZC1(wv4, 4); ZC1(wv5, 5); ZC1(wv6, 6); ZC1(wv7, 7);
      z1part[0][q][s] = za0;
      z1part[1][q][s] = za1;
    }
    __syncthreads();

    // ===== P2: z1 reduce ===================================================
    if (tid < 256) {
      int b = tid >> 7, s = tid & 127;
      float v = b1s[s];
      #pragma unroll
      for (int q2 = 0; q2 < 8; ++q2) v += z1part[b][q2][s];
      z1s[b][s] = v;
    }
    __syncthreads();

    // ===== P3: gates-h stream (kbs 3..31) + E phase, one barrier region ====
    {
      u4 A0, A1, A2, A3, B0, B1, B2, B3, C0;
      A0 = wh4g[ 3*1024+tid]; A1 = wh4g[ 4*1024+tid];
      A2 = wh4g[ 5*1024+tid]; A3 = wh4g[ 6*1024+tid];
      B0 = wh4g[ 7*1024+tid]; B1 = wh4g[ 8*1024+tid];
      B2 = wh4g[ 9*1024+tid]; B3 = wh4g[10*1024+tid];
      {  // E: e[b][n] = sum_s w3[s] * tanh(z1[b][s] + z2[b][n][s])
        int n = tid & 127, b = (tid >> 7) & 1, hf = tid >> 8;
        int s0 = hf * 25, s1 = s0 + ((hf == 3) ? 24 : 25);
        const u16* zr = z2s[b][n];
        float acce = 0.f;
        for (int s = s0; s < s1; ++s)
          acce = fmaf(w3s[s], ftanh(z1s[b][s] + h2ff(zr[s])), acce);
        epart[b][hf][n] = acce;
      }
      HC1(A0,  3); HC1(A1,  4); HC1(A2,  5); HC1(A3,  6);
      A0 = wh4g[11*1024+tid]; A1 = wh4g[12*1024+tid];
      A2 = wh4g[13*1024+tid]; A3 = wh4g[14*1024+tid];
      HC1(B0,  7); HC1(B1,  8); HC1(B2,  9); HC1(B3, 10);
      B0 = wh4g[15*1024+tid]; B1 = wh4g[16*1024+tid];
      B2 = wh4g[17*1024+tid]; B3 = wh4g[18*1024+tid];
      HC1(A0, 11); HC1(A1, 12); HC1(A2, 13); HC1(A3, 14);
      A0 = wh4g[19*1024+tid]; A1 = wh4g[20*1024+tid];
      A2 = wh4g[21*1024+tid]; A3 = wh4g[22*1024+tid];
      HC1(B0, 15); HC1(B1, 16); HC1(B2, 17); HC1(B3, 18);
      B0 = wh4g[23*1024+tid]; B1 = wh4g[24*1024+tid];
      B2 = wh4g[25*1024+tid]; B3 = wh4g[26*1024+tid];
      HC1(A0, 19); HC1(A1, 20); HC1(A2, 21); HC1(A3, 22);
      A0 = wh4g[27*1024+tid]; A1 = wh4g[28*1024+tid];
      A2 = wh4g[29*1024+tid]; A3 = wh4g[30*1024+tid];
      HC1(B0, 23); HC1(B1, 24); HC1(B2, 25); HC1(B3, 26);
      C0 = wh4g[31*1024+tid];
      HC1(A0, 27); HC1(A1, 28); HC1(A2, 29); HC1(A3, 30);
      HC1(C0, 31);
    }
    __syncthreads();

    // ===== P4: issue w-gate loads (latency hides under softmax) + softmax ==
    u4 WA0, WA1, WA2, WA3, WB0, WB1, WB2, WB3;
    WA0 = ww4g[0*1024+tid]; WA1 = ww4g[1*1024+tid];
    WA2 = ww4g[2*1024+tid]; WA3 = ww4g[3*1024+tid];
    WB0 = ww4g[4*1024+tid]; WB1 = ww4g[5*1024+tid];
    WB2 = ww4g[6*1024+tid]; WB3 = ww4g[7*1024+tid];
    if (tid < 128) {
      int b = tid >> 6, ln = tid & 63;
      float v0 = (epart[b][0][ln]      + epart[b][1][ln])
               + (epart[b][2][ln]      + epart[b][3][ln]);
      float v1 = (epart[b][0][ln + 64] + epart[b][1][ln + 64])
               + (epart[b][2][ln + 64] + epart[b][3][ln + 64]);
      float m = fmaxf(v0, v1);
      for (int off = 32; off; off >>= 1) m = fmaxf(m, __shfl_xor(m, off));
      float e0 = __expf(v0 - m), e1 = __expf(v1 - m);
      float sm = e0 + e1;
      for (int off = 32; off; off >>= 1) sm += __shfl_xor(sm, off);
      float r = frcp(sm);
      float w0 = e0 * r * x0v;
      float w1 = e1 * r * x1v;
      float* orow = outw + ((size_t)(b0 + b) * TS + t) * NN;
      orow[ln]      = w0;                // f32 output
      orow[ln + 64] = w1;
      float w0n = __shfl_xor(w0, 1), w1n = __shfl_xor(w1, 1);
      if ((ln & 1) == 0) {               // pack adjacent-n pairs as f16x2
        wp[b][ln >> 1]        = pk2(w0, w0n);
        wp[b][32 + (ln >> 1)] = pk2(w1, w1n);
      }
    }
    __syncthreads();

    // ===== P5: gates-w stream consume (kbs 0..15) + gl write ===============
    {
      WC1(WA0,  0); WC1(WA1,  1); WC1(WA2,  2); WC1(WA3,  3);
      WA0 = ww4g[ 8*1024+tid]; WA1 = ww4g[ 9*1024+tid];
      WA2 = ww4g[10*1024+tid]; WA3 = ww4g[11*1024+tid];
      WC1(WB0,  4); WC1(WB1,  5); WC1(WB2,  6); WC1(WB3,  7);
      WB0 = ww4g[12*1024+tid]; WB1 = ww4g[13*1024+tid];
      WB2 = ww4g[14*1024+tid]; WB3 = ww4g[15*1024+tid];
      WC1(WA0,  8); WC1(WA1,  9); WC1(WA2, 10); WC1(WA3, 11);
      WC1(WB0, 12); WC1(WB1, 13); WC1(WB2, 14); WC1(WB3, 15);
      gl[0][tid] = ga0 + br;
      gl[1][tid] = ga1 + br;
    }
    __syncthreads();

    // ===== P6: LSTM pointwise (tid<512) + h,c repack =======================
    if (tid < 512) {
      float iv = gl[lb][lu],       fv = gl[lb][256 + lu];
      float gv = gl[lb][512 + lu], ov = gl[lb][768 + lu];
      float cn = fsig(fv) * creg + fsig(iv) * ftanh(gv);
      float hn = fsig(ov) * ftanh(cn);
      creg = cn;
      oute[((size_t)(b0 + lb) * TS + t) * HH + lu] = hn;   // f32 output
      float hx = __shfl_xor(hn, 1);      // lu parity == lane parity
      float cx = __shfl_xor(cn, 1);
      if ((lu & 1) == 0) {
        hcp[lb][lu >> 1]         = pk2(hn, hx);
        hcp[lb][128 + (lu >> 1)] = pk2(cn, cx);
      }
    }
    __syncthreads();
  }
}

extern "C" void kernel_launch(void* const* d_in, const int* in_sizes, int n_in,
                              void* d_out, int out_size, void* d_ws, size_t ws_size,
                              hipStream_t stream)
{
  KParams p;
  p.in  = (const float*)d_in[0];
  p.W1  = (const float*)d_in[1];
  p.b1  = (const float*)d_in[2];
  p.W2  = (const float*)d_in[3];
  p.b2  = (const float*)d_in[4];
  p.W3  = (const float*)d_in[5];
  // d_in[6] = b3: softmax shift-invariant, unused
  p.Wih = (const float*)d_in[7];
  p.Whh = (const float*)d_in[8];
  p.bih = (const float*)d_in[9];
  p.bhh = (const float*)d_in[10];
  p.out = (float*)d_out;

  char* ws = (char*)d_ws;
  const size_t wh4Bytes = 32ull * 1024 * 16;           // 524,288
  const size_t ww4Bytes = 16ull * 1024 * 16;           // 262,144
  const size_t w1cBytes = 64ull * 128 * 16;            // 131,072
  const size_t needBytes = wh4Bytes + ww4Bytes + w1cBytes;  // 917,504
  if (ws_size < needBytes) return;  // fail loudly (poisoned output)

  uint32* Wh4 = (uint32*)ws;
  uint32* Ww4 = (uint32*)(ws + wh4Bytes);
  uint32* W1c = (uint32*)(ws + wh4Bytes + ww4Bytes);
  p.Wh4 = (const u4*)Wh4;
  p.Ww4 = (const u4*)Ww4;
  p.W1c = (const u4*)W1c;

  // pack weights (fully covers all buffers; same-stream ordering guarantees
  // visibility; no flags -> no memset needed)
  const int packElems = 32 * 1024 * 4 + 16 * 1024 * 4 + 64 * 128 * 4; // 229,376
  pack_kernel<<<dim3((packElems + 255) / 256), dim3(256), 0, stream>>>(
      p.W1, p.Wih, p.Whh, Wh4, Ww4, W1c);

  enc_kernel<<<dim3(256), dim3(1024), 0, stream>>>(p);
}